// Round 5
// baseline (205.335 us; speedup 1.0000x reference)
//
#include <hip/hip_runtime.h>

// z = segment_sum(x[col], row) @ W.T    (softmax over [E,1] axis=1 == 1)
// Bucket build + per-bucket LDS counting sort + flat 16-deep-ILP gather
// (wave owns 4 contiguous rows -> one contiguous sorted edge range).

#define NBMAX 1600   // buckets = ceil(N/64); N=100000 -> 1563
#define BCAP  2048   // per-tile edge capacity in k_bgather (mean/bucket ~1024)

__global__ __launch_bounds__(1024) void k_ghist(const int* __restrict__ ei,
                                                int* __restrict__ gcnt,
                                                int E, int NB) {
    __shared__ int h[NBMAX];
    for (int i = threadIdx.x; i < NB; i += 1024) h[i] = 0;
    __syncthreads();
    long stride = (long)gridDim.x * 1024;
    for (long i = (long)blockIdx.x * 1024 + threadIdx.x; i < E; i += stride)
        atomicAdd(&h[ei[i] >> 6], 1);
    __syncthreads();
    for (int i = threadIdx.x; i < NB; i += 1024) {
        int v = h[i];
        if (v) atomicAdd(&gcnt[i], v);
    }
}

__global__ __launch_bounds__(1024) void k_gscan(const int* __restrict__ gcnt,
                                                int* __restrict__ boff,
                                                int* __restrict__ gcur,
                                                int NB, int E) {
    __shared__ int a[2048], b2[2048];
    int t = threadIdx.x;
    for (int i = t; i < 2048; i += 1024) a[i] = (i < NB) ? gcnt[i] : 0;
    __syncthreads();
    int* src = a; int* dst = b2;
    for (int s = 1; s < 2048; s <<= 1) {
        for (int i = t; i < 2048; i += 1024)
            dst[i] = src[i] + ((i >= s) ? src[i - s] : 0);
        __syncthreads();
        int* tmp = src; src = dst; dst = tmp;
    }
    for (int i = t; i < NB; i += 1024) {
        int excl = src[i] - gcnt[i];
        boff[i] = excl;
        gcur[i] = excl;
    }
    if (t == 0) boff[NB] = E;
}

// chunk = 8192 edges; LDS hist -> one global atomic per (chunk,bucket) ->
// LDS-cursor scatter of packed 4B records: (row&63)<<26 | col.
__global__ __launch_bounds__(1024) void k_pairs(const int* __restrict__ ei,
                                                int* __restrict__ gcur,
                                                unsigned* __restrict__ pairs,
                                                int E, int NB) {
    __shared__ int hist[NBMAX];
    int t = threadIdx.x;
    long cb = (long)blockIdx.x * 8192;
    for (int i = t; i < NB; i += 1024) hist[i] = 0;
    int rows[8], cols[8];
    #pragma unroll
    for (int u = 0; u < 8; ++u) {
        long i = cb + (long)u * 1024 + t;
        rows[u] = (i < E) ? ei[i] : -1;
        cols[u] = (i < E) ? ei[(long)E + i] : 0;
    }
    __syncthreads();
    #pragma unroll
    for (int u = 0; u < 8; ++u)
        if (rows[u] >= 0) atomicAdd(&hist[rows[u] >> 6], 1);
    __syncthreads();
    for (int b = t; b < NB; b += 1024) {
        int c = hist[b];
        hist[b] = c ? atomicAdd(&gcur[b], c) : 0;
    }
    __syncthreads();
    #pragma unroll
    for (int u = 0; u < 8; ++u)
        if (rows[u] >= 0) {
            int p = atomicAdd(&hist[rows[u] >> 6], 1);
            pairs[p] = ((unsigned)(rows[u] & 63) << 26) | (unsigned)cols[u];
        }
}

// Block (16 waves) per bucket. LDS counting-sort by row, then wave wv owns
// rows 4wv..4wv+3 = ONE contiguous sorted range; flat 16-deep-ILP gather.
__global__ __launch_bounds__(1024, 8) void k_bgather(
    const float* __restrict__ x, const unsigned* __restrict__ pairs,
    const int* __restrict__ boff, const float* __restrict__ W,
    float* __restrict__ out, int N)
{
    __shared__ float w[64][65];       // 16.6KB; (65c+k)%32=(c+k)%32 -> 2-way only
    __shared__ float rowacc[64][64];  // 16KB
    __shared__ unsigned spv[BCAP];    // 8KB
    __shared__ int scol[BCAP];        // 8KB
    __shared__ int cnt[64];
    __shared__ int cs[65];
    int t = threadIdx.x, lane = t & 63, wv = t >> 6;   // 16 waves
    for (int i = t; i < 4096; i += 1024) w[i >> 6][i & 63] = W[i];
    int b = blockIdx.x;
    int s = boff[b], e = boff[b + 1];
    float acc0 = 0.f, acc1 = 0.f, acc2 = 0.f, acc3 = 0.f;

    for (int tile = s; tile < e; tile += BCAP) {
        int m = e - tile; if (m > BCAP) m = BCAP;
        if (t < 64) cnt[t] = 0;
        __syncthreads();
        for (int i = t; i < m; i += 1024) {
            unsigned pv = pairs[tile + i];
            spv[i] = pv;
            atomicAdd(&cnt[pv >> 26], 1);
        }
        __syncthreads();
        if (wv == 0) {                       // 64-wide exclusive scan, wave 0
            int c0 = cnt[lane];
            int v = c0;
            #pragma unroll
            for (int o = 1; o < 64; o <<= 1) {
                int u = __shfl_up(v, o, 64);
                if (lane >= o) v += u;
            }
            cs[lane + 1] = v;
            if (lane == 0) cs[0] = 0;
            cnt[lane] = v - c0;              // cursor = exclusive prefix
        }
        __syncthreads();
        for (int i = t; i < m; i += 1024) {
            unsigned pv = spv[i];
            int p = atomicAdd(&cnt[pv >> 26], 1);
            scol[p] = (int)(pv & 0x3FFFFFFu);
        }
        __syncthreads();

        int ws_ = cs[4 * wv], we_ = cs[4 * wv + 4];      // contiguous 4-row range
        int c1 = cs[4 * wv + 1], c2 = cs[4 * wv + 2], c3 = cs[4 * wv + 3];
        int j = ws_;
        for (; j + 16 <= we_; j += 16) {     // 16 outstanding 256B loads / wave
            int   cc[16]; float vv[16];
            #pragma unroll
            for (int u = 0; u < 16; ++u) cc[u] = scol[j + u];
            #pragma unroll
            for (int u = 0; u < 16; ++u) vv[u] = x[(long)cc[u] * 64 + lane];
            #pragma unroll
            for (int u = 0; u < 16; ++u) {
                int jj = j + u;              // wave-uniform
                int r = (jj >= c1) + (jj >= c2) + (jj >= c3);
                float v = vv[u];
                acc0 += (r == 0) ? v : 0.f;
                acc1 += (r == 1) ? v : 0.f;
                acc2 += (r == 2) ? v : 0.f;
                acc3 += (r == 3) ? v : 0.f;
            }
        }
        for (; j < we_; ++j) {
            float v = x[(long)scol[j] * 64 + lane];
            int r = (j >= c1) + (j >= c2) + (j >= c3);
            acc0 += (r == 0) ? v : 0.f;
            acc1 += (r == 1) ? v : 0.f;
            acc2 += (r == 2) ? v : 0.f;
            acc3 += (r == 3) ? v : 0.f;
        }
        __syncthreads();                     // protect cnt/cs/spv/scol for next tile
    }

    rowacc[4 * wv + 0][lane] = acc0;
    rowacc[4 * wv + 1][lane] = acc1;
    rowacc[4 * wv + 2][lane] = acc2;
    rowacc[4 * wv + 3][lane] = acc3;
    __syncthreads();
    int base = b << 6;
    int nr = N - base; if (nr > 64) nr = 64;
    for (int r = wv; r < nr; r += 16) {
        float z = 0.f;
        #pragma unroll
        for (int k = 0; k < 64; ++k)
            z += rowacc[r][k] * w[lane][k];  // rowacc[r][k] wave-uniform -> broadcast
        out[(long)(base + r) * 64 + lane] = z;
    }
}

// ---- fallback (atomic scatter, R1 path) ----
__global__ __launch_bounds__(256) void egat_scatter(const float* __restrict__ x,
                                                    const int* __restrict__ ei,
                                                    float* __restrict__ out, int E) {
    long tid = (long)blockIdx.x * blockDim.x + threadIdx.x;
    long e = tid >> 4;
    if (e >= E) return;
    int c4 = (int)(tid & 15) << 2;
    int row = ei[e];
    int col = ei[(long)E + e];
    const float4 v = *reinterpret_cast<const float4*>(x + (long)col * 64 + c4);
    float* o = out + (long)row * 64 + c4;
    atomicAdd(o + 0, v.x); atomicAdd(o + 1, v.y);
    atomicAdd(o + 2, v.z); atomicAdd(o + 3, v.w);
}

__global__ __launch_bounds__(256) void egat_transform(float* __restrict__ out,
                                                      const float* __restrict__ W, int N) {
    __shared__ float a[16][64];
    __shared__ float w[64][65];
    int t = threadIdx.x;
    for (int i = t; i < 64 * 64; i += 256) w[i >> 6][i & 63] = W[i];
    long r0 = (long)blockIdx.x * 16;
    int c = t & 63, rb = t >> 6;
    #pragma unroll
    for (int j = 0; j < 4; ++j) {
        long r = r0 + rb + 4 * j;
        if (r < N) a[rb + 4 * j][c] = out[r * 64 + c];
    }
    __syncthreads();
    float acc[4] = {0.f, 0.f, 0.f, 0.f};
    #pragma unroll
    for (int k = 0; k < 64; ++k) {
        float wk = w[c][k];
        #pragma unroll
        for (int j = 0; j < 4; ++j) acc[j] += a[rb + 4 * j][k] * wk;
    }
    #pragma unroll
    for (int j = 0; j < 4; ++j) {
        long r = r0 + rb + 4 * j;
        if (r < N) out[r * 64 + c] = acc[j];
    }
}

extern "C" void kernel_launch(void* const* d_in, const int* in_sizes, int n_in,
                              void* d_out, int out_size, void* d_ws, size_t ws_size,
                              hipStream_t stream)
{
    const float* x  = (const float*)d_in[0];
    const int*   ei = (const int*)d_in[1];
    const float* W  = (const float*)d_in[3];
    float* out = (float*)d_out;

    const int E  = in_sizes[1] / 2;
    const int N  = out_size / 64;
    const int NB = (N + 63) >> 6;

    // ws layout: gcnt[NB] | boff[NB+1] | gcur[NB] | pairs[E]
    size_t need = ((size_t)NB * 3 + 1 + E) * sizeof(int);
    if (NB <= NBMAX && ws_size >= need) {
        int* gcnt = (int*)d_ws;
        int* boff = gcnt + NB;
        int* gcur = boff + (NB + 1);
        unsigned* pairs = (unsigned*)(gcur + NB);

        hipMemsetAsync(gcnt, 0, (size_t)NB * sizeof(int), stream);
        k_ghist<<<128, 1024, 0, stream>>>(ei, gcnt, E, NB);
        k_gscan<<<1, 1024, 0, stream>>>(gcnt, boff, gcur, NB, E);
        k_pairs<<<(E + 8191) / 8192, 1024, 0, stream>>>(ei, gcur, pairs, E, NB);
        k_bgather<<<NB, 1024, 0, stream>>>(x, pairs, boff, W, out, N);
    } else {
        hipMemsetAsync(out, 0, (size_t)N * 64 * sizeof(float), stream);
        long sthreads = (long)E * 16;
        egat_scatter<<<(int)((sthreads + 255) / 256), 256, 0, stream>>>(x, ei, out, E);
        egat_transform<<<(N + 15) / 16, 256, 0, stream>>>(out, W, N);
    }
}

// Round 6
// 188.369 us; speedup vs baseline: 1.0901x; 1.0901x over previous
//
#include <hip/hip_runtime.h>

// z = segment_sum(x[col], row) @ W.T    (softmax over [E,1] axis=1 == 1)
//   = segment_sum((x @ W.T)[col], row)  (linearity)
// Pipeline: bucket build (counting sort by dest, 64 rows/bucket) +
// y = bf16(x@W.T) pre-transform + per-bucket LDS row-sort + segmented
// bf16 gather-sum (128B/edge instead of 256B).

#define NBMAX 1600   // buckets = ceil(N/64); N=100000 -> 1563
#define BCAP  2048   // per-tile edge capacity (mean/bucket ~1024)

__global__ __launch_bounds__(1024) void k_ghist(const int* __restrict__ ei,
                                                int* __restrict__ gcnt,
                                                int E, int NB) {
    __shared__ int h[NBMAX];
    for (int i = threadIdx.x; i < NB; i += 1024) h[i] = 0;
    __syncthreads();
    long stride = (long)gridDim.x * 1024;
    for (long i = (long)blockIdx.x * 1024 + threadIdx.x; i < E; i += stride)
        atomicAdd(&h[ei[i] >> 6], 1);
    __syncthreads();
    for (int i = threadIdx.x; i < NB; i += 1024) {
        int v = h[i];
        if (v) atomicAdd(&gcnt[i], v);
    }
}

__global__ __launch_bounds__(1024) void k_gscan(const int* __restrict__ gcnt,
                                                int* __restrict__ boff,
                                                int* __restrict__ gcur,
                                                int NB, int E) {
    __shared__ int a[2048], b2[2048];
    int t = threadIdx.x;
    for (int i = t; i < 2048; i += 1024) a[i] = (i < NB) ? gcnt[i] : 0;
    __syncthreads();
    int* src = a; int* dst = b2;
    for (int s = 1; s < 2048; s <<= 1) {
        for (int i = t; i < 2048; i += 1024)
            dst[i] = src[i] + ((i >= s) ? src[i - s] : 0);
        __syncthreads();
        int* tmp = src; src = dst; dst = tmp;
    }
    for (int i = t; i < NB; i += 1024) {
        int excl = src[i] - gcnt[i];
        boff[i] = excl;
        gcur[i] = excl;
    }
    if (t == 0) boff[NB] = E;
}

__global__ __launch_bounds__(1024) void k_pairs(const int* __restrict__ ei,
                                                int* __restrict__ gcur,
                                                unsigned* __restrict__ pairs,
                                                int E, int NB) {
    __shared__ int hist[NBMAX];
    int t = threadIdx.x;
    long cb = (long)blockIdx.x * 8192;
    for (int i = t; i < NB; i += 1024) hist[i] = 0;
    int rows[8], cols[8];
    #pragma unroll
    for (int u = 0; u < 8; ++u) {
        long i = cb + (long)u * 1024 + t;
        rows[u] = (i < E) ? ei[i] : -1;
        cols[u] = (i < E) ? ei[(long)E + i] : 0;
    }
    __syncthreads();
    #pragma unroll
    for (int u = 0; u < 8; ++u)
        if (rows[u] >= 0) atomicAdd(&hist[rows[u] >> 6], 1);
    __syncthreads();
    for (int b = t; b < NB; b += 1024) {
        int c = hist[b];
        hist[b] = c ? atomicAdd(&gcur[b], c) : 0;
    }
    __syncthreads();
    #pragma unroll
    for (int u = 0; u < 8; ++u)
        if (rows[u] >= 0) {
            int p = atomicAdd(&hist[rows[u] >> 6], 1);
            pairs[p] = ((unsigned)(rows[u] & 63) << 26) | (unsigned)cols[u];
        }
}

// y[n][c] = bf16( sum_k x[n][k] * W[c][k] )
__global__ __launch_bounds__(256) void k_ytrans(const float* __restrict__ x,
                                                const float* __restrict__ W,
                                                unsigned short* __restrict__ y, int N) {
    __shared__ float a[16][64];
    __shared__ float w[64][65];   // (65c+k)%32=(c+k)%32 -> 2-way alias only (free)
    int t = threadIdx.x;
    for (int i = t; i < 4096; i += 256) w[i >> 6][i & 63] = W[i];
    long r0 = (long)blockIdx.x * 16;
    int c = t & 63, rb = t >> 6;
    #pragma unroll
    for (int j = 0; j < 4; ++j) {
        long r = r0 + rb + 4 * j;
        if (r < N) a[rb + 4 * j][c] = x[r * 64 + c];
    }
    __syncthreads();
    float acc[4] = {0.f, 0.f, 0.f, 0.f};
    #pragma unroll
    for (int k = 0; k < 64; ++k) {
        float wk = w[c][k];
        #pragma unroll
        for (int j = 0; j < 4; ++j) acc[j] += a[rb + 4 * j][k] * wk;
    }
    #pragma unroll
    for (int j = 0; j < 4; ++j) {
        long r = r0 + rb + 4 * j;
        if (r < N) {
            unsigned u = __float_as_uint(acc[j]);
            u = (u + 0x7fffu + ((u >> 16) & 1u)) >> 16;   // RNE to bf16
            y[r * 64 + c] = (unsigned short)u;
        }
    }
}

__device__ __forceinline__ float bf2f(unsigned short u) {
    return __uint_as_float(((unsigned)u) << 16);
}

__device__ __forceinline__ void seg_sum(const unsigned short* __restrict__ y,
                                        const int* scol, int rs, int re,
                                        int lane, float& acc) {
    int j = rs;
    for (; j + 8 <= re; j += 8) {        // 8 outstanding 128B row-loads
        int c0 = scol[j], c1 = scol[j+1], c2 = scol[j+2], c3 = scol[j+3];
        int c4 = scol[j+4], c5 = scol[j+5], c6 = scol[j+6], c7 = scol[j+7];
        float v0 = bf2f(y[(c0 << 6) + lane]);
        float v1 = bf2f(y[(c1 << 6) + lane]);
        float v2 = bf2f(y[(c2 << 6) + lane]);
        float v3 = bf2f(y[(c3 << 6) + lane]);
        float v4 = bf2f(y[(c4 << 6) + lane]);
        float v5 = bf2f(y[(c5 << 6) + lane]);
        float v6 = bf2f(y[(c6 << 6) + lane]);
        float v7 = bf2f(y[(c7 << 6) + lane]);
        acc += ((v0 + v1) + (v2 + v3)) + ((v4 + v5) + (v6 + v7));
    }
    for (; j + 4 <= re; j += 4) {
        int c0 = scol[j], c1 = scol[j+1], c2 = scol[j+2], c3 = scol[j+3];
        float v0 = bf2f(y[(c0 << 6) + lane]);
        float v1 = bf2f(y[(c1 << 6) + lane]);
        float v2 = bf2f(y[(c2 << 6) + lane]);
        float v3 = bf2f(y[(c3 << 6) + lane]);
        acc += (v0 + v1) + (v2 + v3);
    }
    for (; j < re; ++j) acc += bf2f(y[(scol[j] << 6) + lane]);
}

// Block (16 waves) per bucket; LDS counting-sort by row; wave wv owns rows
// 4wv..4wv+3 (per-row segmented loops, no classification VALU); direct out.
__global__ __launch_bounds__(1024, 8) void k_bgather16(
    const unsigned short* __restrict__ y, const unsigned* __restrict__ pairs,
    const int* __restrict__ boff, float* __restrict__ out, int N)
{
    __shared__ unsigned spv[BCAP];    // 8KB
    __shared__ int scol[BCAP];        // 8KB
    __shared__ int cnt[64];
    __shared__ int cs[65];
    int t = threadIdx.x, lane = t & 63, wv = t >> 6;   // 16 waves
    int b = blockIdx.x;
    int s = boff[b], e = boff[b + 1];
    float acc0 = 0.f, acc1 = 0.f, acc2 = 0.f, acc3 = 0.f;

    for (int tile = s; tile < e; tile += BCAP) {
        int m = e - tile; if (m > BCAP) m = BCAP;
        if (t < 64) cnt[t] = 0;
        __syncthreads();
        for (int i = t; i < m; i += 1024) {
            unsigned pv = pairs[tile + i];
            spv[i] = pv;
            atomicAdd(&cnt[pv >> 26], 1);
        }
        __syncthreads();
        if (wv == 0) {                       // 64-wide exclusive scan, wave 0
            int c0 = cnt[lane];
            int v = c0;
            #pragma unroll
            for (int o = 1; o < 64; o <<= 1) {
                int u = __shfl_up(v, o, 64);
                if (lane >= o) v += u;
            }
            cs[lane + 1] = v;
            if (lane == 0) cs[0] = 0;
            cnt[lane] = v - c0;              // cursor = exclusive prefix
        }
        __syncthreads();
        for (int i = t; i < m; i += 1024) {
            unsigned pv = spv[i];
            int p = atomicAdd(&cnt[pv >> 26], 1);
            scol[p] = (int)(pv & 0x3FFFFFFu);
        }
        __syncthreads();

        int r4 = wv << 2;
        int b0 = cs[r4], b1 = cs[r4 + 1], b2 = cs[r4 + 2];
        int b3 = cs[r4 + 3], b4 = cs[r4 + 4];
        seg_sum(y, scol, b0, b1, lane, acc0);
        seg_sum(y, scol, b1, b2, lane, acc1);
        seg_sum(y, scol, b2, b3, lane, acc2);
        seg_sum(y, scol, b3, b4, lane, acc3);
        __syncthreads();                     // protect cnt/cs/spv/scol for next tile
    }

    int base = (b << 6) + (wv << 2);
    if (base + 0 < N) out[(long)(base + 0) * 64 + lane] = acc0;
    if (base + 1 < N) out[(long)(base + 1) * 64 + lane] = acc1;
    if (base + 2 < N) out[(long)(base + 2) * 64 + lane] = acc2;
    if (base + 3 < N) out[(long)(base + 3) * 64 + lane] = acc3;
}

// ---- tier-2 fallback: f32 gather with fused transform (R5 path) ----
__global__ __launch_bounds__(1024, 8) void k_bgather(
    const float* __restrict__ x, const unsigned* __restrict__ pairs,
    const int* __restrict__ boff, const float* __restrict__ W,
    float* __restrict__ out, int N)
{
    __shared__ float w[64][65];
    __shared__ float rowacc[64][64];
    __shared__ unsigned spv[BCAP];
    __shared__ int scol[BCAP];
    __shared__ int cnt[64];
    __shared__ int cs[65];
    int t = threadIdx.x, lane = t & 63, wv = t >> 6;
    for (int i = t; i < 4096; i += 1024) w[i >> 6][i & 63] = W[i];
    int b = blockIdx.x;
    int s = boff[b], e = boff[b + 1];
    float acc0 = 0.f, acc1 = 0.f, acc2 = 0.f, acc3 = 0.f;
    for (int tile = s; tile < e; tile += BCAP) {
        int m = e - tile; if (m > BCAP) m = BCAP;
        if (t < 64) cnt[t] = 0;
        __syncthreads();
        for (int i = t; i < m; i += 1024) {
            unsigned pv = pairs[tile + i];
            spv[i] = pv;
            atomicAdd(&cnt[pv >> 26], 1);
        }
        __syncthreads();
        if (wv == 0) {
            int c0 = cnt[lane];
            int v = c0;
            #pragma unroll
            for (int o = 1; o < 64; o <<= 1) {
                int u = __shfl_up(v, o, 64);
                if (lane >= o) v += u;
            }
            cs[lane + 1] = v;
            if (lane == 0) cs[0] = 0;
            cnt[lane] = v - c0;
        }
        __syncthreads();
        for (int i = t; i < m; i += 1024) {
            unsigned pv = spv[i];
            int p = atomicAdd(&cnt[pv >> 26], 1);
            scol[p] = (int)(pv & 0x3FFFFFFu);
        }
        __syncthreads();
        int r4 = wv << 2;
        int c1 = cs[r4 + 1], c2 = cs[r4 + 2], c3 = cs[r4 + 3];
        int j = cs[r4], we_ = cs[r4 + 4];
        for (; j + 4 <= we_; j += 4) {
            int c0_ = scol[j], c1_ = scol[j+1], c2_ = scol[j+2], c3_ = scol[j+3];
            float v0 = x[(long)c0_ * 64 + lane];
            float v1 = x[(long)c1_ * 64 + lane];
            float v2 = x[(long)c2_ * 64 + lane];
            float v3 = x[(long)c3_ * 64 + lane];
            #pragma unroll
            for (int u = 0; u < 4; ++u) {
                int jj = j + u;
                float v = (u == 0) ? v0 : (u == 1) ? v1 : (u == 2) ? v2 : v3;
                int r = (jj >= c1) + (jj >= c2) + (jj >= c3);
                acc0 += (r == 0) ? v : 0.f;
                acc1 += (r == 1) ? v : 0.f;
                acc2 += (r == 2) ? v : 0.f;
                acc3 += (r == 3) ? v : 0.f;
            }
        }
        for (; j < we_; ++j) {
            float v = x[(long)scol[j] * 64 + lane];
            int r = (j >= c1) + (j >= c2) + (j >= c3);
            acc0 += (r == 0) ? v : 0.f;
            acc1 += (r == 1) ? v : 0.f;
            acc2 += (r == 2) ? v : 0.f;
            acc3 += (r == 3) ? v : 0.f;
        }
        __syncthreads();
    }
    rowacc[4 * wv + 0][lane] = acc0;
    rowacc[4 * wv + 1][lane] = acc1;
    rowacc[4 * wv + 2][lane] = acc2;
    rowacc[4 * wv + 3][lane] = acc3;
    __syncthreads();
    int base = b << 6;
    int nr = N - base; if (nr > 64) nr = 64;
    for (int r = wv; r < nr; r += 16) {
        float z = 0.f;
        #pragma unroll
        for (int k = 0; k < 64; ++k)
            z += rowacc[r][k] * w[lane][k];
        out[(long)(base + r) * 64 + lane] = z;
    }
}

// ---- tier-3 fallback (atomic scatter) ----
__global__ __launch_bounds__(256) void egat_scatter(const float* __restrict__ x,
                                                    const int* __restrict__ ei,
                                                    float* __restrict__ out, int E) {
    long tid = (long)blockIdx.x * blockDim.x + threadIdx.x;
    long e = tid >> 4;
    if (e >= E) return;
    int c4 = (int)(tid & 15) << 2;
    int row = ei[e];
    int col = ei[(long)E + e];
    const float4 v = *reinterpret_cast<const float4*>(x + (long)col * 64 + c4);
    float* o = out + (long)row * 64 + c4;
    atomicAdd(o + 0, v.x); atomicAdd(o + 1, v.y);
    atomicAdd(o + 2, v.z); atomicAdd(o + 3, v.w);
}

__global__ __launch_bounds__(256) void egat_transform(float* __restrict__ out,
                                                      const float* __restrict__ W, int N) {
    __shared__ float a[16][64];
    __shared__ float w[64][65];
    int t = threadIdx.x;
    for (int i = t; i < 64 * 64; i += 256) w[i >> 6][i & 63] = W[i];
    long r0 = (long)blockIdx.x * 16;
    int c = t & 63, rb = t >> 6;
    #pragma unroll
    for (int j = 0; j < 4; ++j) {
        long r = r0 + rb + 4 * j;
        if (r < N) a[rb + 4 * j][c] = out[r * 64 + c];
    }
    __syncthreads();
    float acc[4] = {0.f, 0.f, 0.f, 0.f};
    #pragma unroll
    for (int k = 0; k < 64; ++k) {
        float wk = w[c][k];
        #pragma unroll
        for (int j = 0; j < 4; ++j) acc[j] += a[rb + 4 * j][k] * wk;
    }
    #pragma unroll
    for (int j = 0; j < 4; ++j) {
        long r = r0 + rb + 4 * j;
        if (r < N) out[r * 64 + c] = acc[j];
    }
}

extern "C" void kernel_launch(void* const* d_in, const int* in_sizes, int n_in,
                              void* d_out, int out_size, void* d_ws, size_t ws_size,
                              hipStream_t stream)
{
    const float* x  = (const float*)d_in[0];
    const int*   ei = (const int*)d_in[1];
    const float* W  = (const float*)d_in[3];
    float* out = (float*)d_out;

    const int E  = in_sizes[1] / 2;
    const int N  = out_size / 64;
    const int NB = (N + 63) >> 6;

    // ws layout: gcnt[NB] | boff[NB+1] | gcur[NB] | pairs[E] | y[N*64 bf16]
    size_t need_ints = ((size_t)NB * 3 + 1 + E) * sizeof(int);
    size_t need_bf16 = need_ints + (size_t)N * 64 * sizeof(unsigned short);
    if (NB <= NBMAX && ws_size >= need_bf16) {
        int* gcnt = (int*)d_ws;
        int* boff = gcnt + NB;
        int* gcur = boff + (NB + 1);
        unsigned* pairs = (unsigned*)(gcur + NB);
        unsigned short* y = (unsigned short*)(pairs + E);

        hipMemsetAsync(gcnt, 0, (size_t)NB * sizeof(int), stream);
        k_ghist<<<128, 1024, 0, stream>>>(ei, gcnt, E, NB);
        k_gscan<<<1, 1024, 0, stream>>>(gcnt, boff, gcur, NB, E);
        k_pairs<<<(E + 8191) / 8192, 1024, 0, stream>>>(ei, gcur, pairs, E, NB);
        k_ytrans<<<(N + 15) / 16, 256, 0, stream>>>(x, W, y, N);
        k_bgather16<<<NB, 1024, 0, stream>>>(y, pairs, boff, out, N);
    } else if (NB <= NBMAX && ws_size >= need_ints) {
        int* gcnt = (int*)d_ws;
        int* boff = gcnt + NB;
        int* gcur = boff + (NB + 1);
        unsigned* pairs = (unsigned*)(gcur + NB);

        hipMemsetAsync(gcnt, 0, (size_t)NB * sizeof(int), stream);
        k_ghist<<<128, 1024, 0, stream>>>(ei, gcnt, E, NB);
        k_gscan<<<1, 1024, 0, stream>>>(gcnt, boff, gcur, NB, E);
        k_pairs<<<(E + 8191) / 8192, 1024, 0, stream>>>(ei, gcur, pairs, E, NB);
        k_bgather<<<NB, 1024, 0, stream>>>(x, pairs, boff, W, out, N);
    } else {
        hipMemsetAsync(out, 0, (size_t)N * 64 * sizeof(float), stream);
        long sthreads = (long)E * 16;
        egat_scatter<<<(int)((sthreads + 255) / 256), 256, 0, stream>>>(x, ei, out, E);
        egat_transform<<<(N + 15) / 16, 256, 0, stream>>>(out, W, N);
    }
}